// Round 2
// baseline (530.445 us; speedup 1.0000x reference)
//
#include <hip/hip_runtime.h>

// Momentum linear attention, fp32.
//   Qf = (elu(Q)+1)*scale
//   Kf = (elu(K)+1)*mask*scale*mw(l),  mw(l) = (1 - 0.9^(L-l))/0.1  (l 0-based)
//   Vf = V*mask
//   KV[bh] = Kf^T Vf   (128x128)
//   X = Qf * KV
#define B_ 2
#define H_ 16
#define L_ 8192
#define D_ 128
#define BH_ (B_*H_)

#define SPLIT 16            // L-chunks per (b,h) for KV phase
#define ROWS1 (L_/SPLIT)    // 512 rows per block
#define TL 16               // l-tile staged in LDS

#define ROWS2 128           // Q rows per chunk in X phase
#define XBLKS 8             // blocks per (b,h) in X phase
#define NCH (L_/(ROWS2*XBLKS))  // 8 chunks per block

#define SCALE  0.10511205190671431f   // 8192^-0.25
#define LOG2MU -0.15200309344504997f  // log2(0.9)

static __device__ __forceinline__ int swz(int j){ return j ^ (j>>3); }  // bijective in [0,32)

static __device__ __forceinline__ float elu1(float x){ return x > 0.f ? x + 1.f : __expf(x); }
static __device__ __forceinline__ float4 elu1s(float4 q, float s){
  float4 r; r.x=elu1(q.x)*s; r.y=elu1(q.y)*s; r.z=elu1(q.z)*s; r.w=elu1(q.w)*s; return r;
}
static __device__ __forceinline__ float4 scal4(float4 q, float s){
  q.x*=s; q.y*=s; q.z*=s; q.w*=s; return q;
}

// ---------------- Phase 1: KV = Kf^T Vf (partial per L-split) ----------------
template<bool ATOMIC>
__global__ __launch_bounds__(256,2) void kv_partial_k(const float* __restrict__ Kg,
    const float* __restrict__ Vg, const float* __restrict__ Mg, float* __restrict__ outg)
{
  __shared__ float Kt[TL][D_];
  __shared__ float Vt[TL][D_];   // float4-index swizzled rows
  const int t  = threadIdx.x;
  const int bh = blockIdx.x / SPLIT;
  const int sp = blockIdx.x % SPLIT;
  const int b  = bh / H_;
  const float* Kp = Kg + (size_t)bh*L_*D_;
  const float* Vp = Vg + (size_t)bh*L_*D_;
  const float* mp = Mg + (size_t)b*L_;
  const int l0   = sp*ROWS1;
  const int srow = t>>4;          // staging: 16 rows x 16 col-groups
  const int scol = (t&15)*8;
  const int tx = t&15, ty = t>>4; // compute: thread owns d-rows ty*8.., e-cols tx*8..

  float acc[8][8];
  #pragma unroll
  for (int i=0;i<8;i++)
    #pragma unroll
    for (int j=0;j<8;j++) acc[i][j]=0.f;

  float4 ck0,ck1,cv0,cv1; float ckw, cvw;
  { // load tile 0
    const int l = l0 + srow;
    const float m = mp[l];
    const float p = exp2f((float)(L_-l)*LOG2MU);
    ckw = m * (10.0f*SCALE) * (1.0f-p);   // mask*scale*mw
    cvw = m;
    const float4* ks = (const float4*)(Kp + (size_t)l*D_ + scol);
    const float4* vs = (const float4*)(Vp + (size_t)l*D_ + scol);
    ck0=ks[0]; ck1=ks[1]; cv0=vs[0]; cv1=vs[1];
  }

  const int NT = ROWS1/TL;
  for (int tile=0; tile<NT; ++tile){
    if (tile) __syncthreads();            // previous tile's readers done
    *(float4*)&Kt[srow][scol]   = elu1s(ck0, ckw);
    *(float4*)&Kt[srow][scol+4] = elu1s(ck1, ckw);
    float4* vrow = (float4*)&Vt[srow][0];
    vrow[swz(2*(t&15))]   = scal4(cv0, cvw);
    vrow[swz(2*(t&15)+1)] = scal4(cv1, cvw);
    __syncthreads();
    if (tile+1 < NT){                     // prefetch next tile (hides HBM under compute)
      const int l = l0 + (tile+1)*TL + srow;
      const float m = mp[l];
      const float p = exp2f((float)(L_-l)*LOG2MU);
      ckw = m * (10.0f*SCALE) * (1.0f-p);
      cvw = m;
      const float4* ks = (const float4*)(Kp + (size_t)l*D_ + scol);
      const float4* vs = (const float4*)(Vp + (size_t)l*D_ + scol);
      ck0=ks[0]; ck1=ks[1]; cv0=vs[0]; cv1=vs[1];
    }
    #pragma unroll 4
    for (int ll=0; ll<TL; ++ll){
      float4 a0 = *(const float4*)&Kt[ll][ty*8];     // 4 distinct addrs/wave (16-way bcast): conflict-free
      float4 a1 = *(const float4*)&Kt[ll][ty*8+4];
      const float4* vr = (const float4*)&Vt[ll][0];
      float4 b0 = vr[swz(2*tx)];                     // swizzle: 4-way -> 2-way (free)
      float4 b1 = vr[swz(2*tx+1)];
      float a[8]={a0.x,a0.y,a0.z,a0.w,a1.x,a1.y,a1.z,a1.w};
      float bb[8]={b0.x,b0.y,b0.z,b0.w,b1.x,b1.y,b1.z,b1.w};
      #pragma unroll
      for (int i=0;i<8;i++)
        #pragma unroll
        for (int j=0;j<8;j++) acc[i][j] = fmaf(a[i], bb[j], acc[i][j]);
    }
  }

  if (ATOMIC){
    float* kvb = outg + ((size_t)bh<<14);
    #pragma unroll
    for (int i=0;i<8;i++){
      const int d = ty*8+i;
      #pragma unroll
      for (int j=0;j<8;j++) atomicAdd(&kvb[d*D_ + tx*8 + j], acc[i][j]);
    }
  } else {
    float* op = outg + (((size_t)bh*SPLIT + sp)<<14);
    #pragma unroll
    for (int i=0;i<8;i++){
      const int d = ty*8+i;
      *(float4*)&op[d*D_ + tx*8]   = make_float4(acc[i][0],acc[i][1],acc[i][2],acc[i][3]);
      *(float4*)&op[d*D_ + tx*8+4] = make_float4(acc[i][4],acc[i][5],acc[i][6],acc[i][7]);
    }
  }
}

// ---------------- Phase 1.5: reduce partials ----------------
__global__ __launch_bounds__(256) void kv_reduce_k(const float* __restrict__ part,
                                                   float* __restrict__ kv)
{
  const int idx = blockIdx.x*256 + threadIdx.x;   // over BH_*D_*D_
  const int bh  = idx >> 14;
  const int de  = idx & 16383;
  const float* p = part + (((size_t)bh*SPLIT)<<14) + de;
  float s = 0.f;
  #pragma unroll
  for (int sp=0; sp<SPLIT; ++sp) s += p[(size_t)sp<<14];
  kv[idx] = s;
}

// ---------------- Phase 2: X = Qf * KV ----------------
__global__ __launch_bounds__(512,2) void x_k(const float* __restrict__ Qg,
    const float* __restrict__ kv, float* __restrict__ Xg)
{
  __shared__ float KVs[D_][D_];      // 64 KiB, float4-index swizzled rows
  __shared__ float Qs[ROWS2][D_+4];  // pad to stride 132: row reads 2-way (free)
  const int t   = threadIdx.x;
  const int bh  = blockIdx.x >> 3;
  const int sub = blockIdx.x & 7;
  const float* Qbh = Qg + (size_t)bh*L_*D_;
  float* Xbh = Xg + (size_t)bh*L_*D_;

  { // stage KV once per block
    const float4* kvsrc = (const float4*)(kv + ((size_t)bh<<14));
    float4 kvreg[8];
    #pragma unroll
    for (int i=0;i<8;i++) kvreg[i] = kvsrc[t + 512*i];
    #pragma unroll
    for (int i=0;i<8;i++){
      int F = t + 512*i;
      ((float4*)&KVs[F>>5][0])[swz(F&31)] = kvreg[i];
    }
  }
  int ch = sub;
  float4 qreg[8];
  { // first Q chunk
    const float4* qs = (const float4*)(Qbh + (size_t)ch*ROWS2*D_);
    #pragma unroll
    for (int i=0;i<8;i++) qreg[i] = qs[t + 512*i];
  }
  #pragma unroll
  for (int i=0;i<8;i++){
    float4 q = elu1s(qreg[i], SCALE);
    int F = t + 512*i;
    *(float4*)&Qs[F>>5][(F&31)*4] = q;
  }
  __syncthreads();

  const int rg = t>>4;   // 32 row-groups of 4 rows
  const int ct = t&15;   // 16 col-groups of 8 cols

  for (int k=0;;){
    if (k+1 < NCH){      // issue next chunk's loads early; latency hides under compute
      const float4* qs = (const float4*)(Qbh + (size_t)(ch+XBLKS)*ROWS2*D_);
      #pragma unroll
      for (int i=0;i<8;i++) qreg[i] = qs[t + 512*i];
    }
    float acc[4][8];
    #pragma unroll
    for (int i=0;i<4;i++)
      #pragma unroll
      for (int j=0;j<8;j++) acc[i][j]=0.f;
    #pragma unroll 4
    for (int d=0; d<D_; ++d){
      const float4* kr = (const float4*)&KVs[d][0];
      float4 b0 = kr[swz(2*ct)];
      float4 b1 = kr[swz(2*ct+1)];
      float qq[4] = { Qs[rg*4+0][d], Qs[rg*4+1][d], Qs[rg*4+2][d], Qs[rg*4+3][d] };
      float bb[8]={b0.x,b0.y,b0.z,b0.w,b1.x,b1.y,b1.z,b1.w};
      #pragma unroll
      for (int i=0;i<4;i++)
        #pragma unroll
        for (int j=0;j<8;j++) acc[i][j] = fmaf(qq[i], bb[j], acc[i][j]);
    }
    float* xp = Xbh + ((size_t)ch*ROWS2 + rg*4)*D_ + ct*8;
    #pragma unroll
    for (int i=0;i<4;i++){
      *(float4*)&xp[i*D_]   = make_float4(acc[i][0],acc[i][1],acc[i][2],acc[i][3]);
      *(float4*)&xp[i*D_+4] = make_float4(acc[i][4],acc[i][5],acc[i][6],acc[i][7]);
    }
    ++k;
    if (k == NCH) break;
    ch += XBLKS;
    __syncthreads();
    #pragma unroll
    for (int i=0;i<8;i++){
      float4 q = elu1s(qreg[i], SCALE);
      int F = t + 512*i;
      *(float4*)&Qs[F>>5][(F&31)*4] = q;
    }
    __syncthreads();
  }
}

extern "C" void kernel_launch(void* const* d_in, const int* in_sizes, int n_in,
                              void* d_out, int out_size, void* d_ws, size_t ws_size,
                              hipStream_t stream)
{
  const float* Q = (const float*)d_in[0];
  const float* K = (const float*)d_in[1];
  const float* V = (const float*)d_in[2];
  const float* M = (const float*)d_in[3];
  float* X  = (float*)d_out;
  float* ws = (float*)d_ws;

  const size_t part_elems = (size_t)BH_*SPLIT*D_*D_;  // 8.39M floats = 33.6 MB
  const size_t kv_elems   = (size_t)BH_*D_*D_;        // 2 MiB

  if (ws_size >= (part_elems + kv_elems)*sizeof(float)){
    float* part = ws;
    float* kvb  = ws + part_elems;
    kv_partial_k<false><<<dim3(BH_*SPLIT), dim3(256), 0, stream>>>(K, V, M, part);
    kv_reduce_k<<<dim3((BH_*D_*D_)/256), dim3(256), 0, stream>>>(part, kvb);
    x_k<<<dim3(BH_*XBLKS), dim3(512), 0, stream>>>(Q, kvb, X);
  } else {
    float* kvb = ws;  // atomic fallback if workspace is small
    hipMemsetAsync(kvb, 0, kv_elems*sizeof(float), stream);
    kv_partial_k<true><<<dim3(BH_*SPLIT), dim3(256), 0, stream>>>(K, V, M, kvb);
    x_k<<<dim3(BH_*XBLKS), dim3(512), 0, stream>>>(Q, kvb, X);
  }
}